// Round 9
// baseline (325.999 us; speedup 1.0000x reference)
//
#include <hip/hip_runtime.h>
#include <math.h>

__device__ __forceinline__ float rcp_(float x) { return __fdividef(1.0f, x); }

// tanh via [9/8] continued-fraction Pade, t = x^2; 1 rcp, no exp.
__device__ __forceinline__ float tanh_(float x) {
    float t = x * x;
    float p = t + 378.0f;
    p = fmaf(p, t, 17325.0f);
    p = fmaf(p, t, 135135.0f);
    float q = fmaf(28.0f, t, 3150.0f);
    q = fmaf(q, t, 62370.0f);
    q = fmaf(q, t, 135135.0f);
    float r = (x * p) * rcp_(q);
    return fminf(fmaxf(r, -1.0f), 1.0f);
}

// EXACT: softplus(softplus(x)) = log(2 + e^x)
__device__ __forceinline__ float sp2_(float x) {
    return __logf(2.0f + __expf(x));
}

// w[k] = 0.001 + 0.995 * softmax(6*softmax(o))[k]; shift-invariance -> no max needed
__device__ __forceinline__ void dsm5_(float o0, float o1, float o2, float o3, float o4,
                                      float* __restrict__ w) {
    float e0 = __expf(o0), e1 = __expf(o1), e2 = __expf(o2),
          e3 = __expf(o3), e4 = __expf(o4);
    float inv = 6.0f * rcp_(((e0 + e1) + (e2 + e3)) + e4);
    float f0 = __expf(e0 * inv);
    float f1 = __expf(e1 * inv);
    float f2 = __expf(e2 * inv);
    float f3 = __expf(e3 * inv);
    float f4 = __expf(e4 * inv);
    float t = 0.995f * rcp_(((f0 + f1) + (f2 + f3)) + f4);
    w[0] = fmaf(f0, t, 0.001f);
    w[1] = fmaf(f1, t, 0.001f);
    w[2] = fmaf(f2, t, 0.001f);
    w[3] = fmaf(f3, t, 0.001f);
    w[4] = fmaf(f4, t, 0.001f);
}

__global__ __launch_bounds__(512)
void nsf_kernel(const float* __restrict__ x_inp, const float* __restrict__ cond_inp,
                const float* __restrict__ Wi1, const float* __restrict__ bi1,
                const float* __restrict__ Wi2, const float* __restrict__ bi2,
                const float* __restrict__ Wi3, const float* __restrict__ bi3,
                const float* __restrict__ Wf1, const float* __restrict__ bf1,
                const float* __restrict__ Wf2, const float* __restrict__ bf2,
                const float* __restrict__ Wf3, const float* __restrict__ bf3,
                float* __restrict__ out, int N)
{
    const int lane = threadIdx.x;                 // 0..63 sample-in-block
    const int jd   = threadIdx.y;                 // 0..7 dim (one wave per dim)
    const int jdu  = __builtin_amdgcn_readfirstlane(jd);
    int s = blockIdx.x * 64 + lane;
    int sl = (s < N) ? s : (N - 1);

    // ---------------- inputs ----------------
    float c16[16];
    {
        const float4* cp = (const float4*)(cond_inp + (size_t)sl * 16);
        float4 c0 = cp[0], c1 = cp[1], c2 = cp[2], c3 = cp[3];
        c16[0]=c0.x;  c16[1]=c0.y;  c16[2]=c0.z;  c16[3]=c0.w;
        c16[4]=c1.x;  c16[5]=c1.y;  c16[6]=c1.z;  c16[7]=c1.w;
        c16[8]=c2.x;  c16[9]=c2.y;  c16[10]=c2.z; c16[11]=c2.w;
        c16[12]=c3.x; c16[13]=c3.y; c16[14]=c3.z; c16[15]=c3.w;
    }
    float xv[8];
    {
        const float4* xp = (const float4*)(x_inp + (size_t)sl * 8);
        float4 a0 = xp[0], b0 = xp[1];
        xv[0]=a0.x; xv[1]=a0.y; xv[2]=a0.z; xv[3]=a0.w;
        xv[4]=b0.x; xv[5]=b0.y; xv[6]=b0.z; xv[7]=b0.w;
    }
    // xcur = xv[jd] via static select chain (no runtime array index)
    float xcur = xv[0];
#pragma unroll
    for (int t = 1; t < 8; ++t) xcur = (jd == t) ? xv[t] : xcur;

    // ---------------- Phase 1: L1 of all three nets, c-outer ----------------
    // a[0..7] gaussian, a[8..15] flow0, a[16..23] flow1
    const float* Wg1 = Wi1 + (size_t)jdu * 184;
    const float* Wa1 = Wf1 + (size_t)(2 * jdu) * 184;
    const float* Wb1 = Wf1 + (size_t)(2 * jdu + 1) * 184;
    float a[24];
#pragma unroll
    for (int i = 0; i < 8; ++i) {
        a[i]      = bi1[jdu * 8 + i];
        a[8 + i]  = bf1[(2 * jdu) * 8 + i];
        a[16 + i] = bf1[(2 * jdu + 1) * 8 + i];
    }
#pragma unroll
    for (int c = 0; c < 23; ++c) {
        float v;
        if (c < 16) v = c16[c];
        else        v = (c - 16 < jd) ? xv[c - 16] : 0.0f;
#pragma unroll
        for (int i = 0; i < 8; ++i) {
            a[i]      = fmaf(Wg1[i * 23 + c], v, a[i]);
            a[8 + i]  = fmaf(Wa1[i * 23 + c], v, a[8 + i]);
            a[16 + i] = fmaf(Wb1[i * 23 + c], v, a[16 + i]);
        }
    }
    float h[24];
#pragma unroll
    for (int i = 0; i < 24; ++i) h[i] = tanh_(a[i]);

    // ---------------- Phase 2: L2 of all three nets ----------------
    const float* Wg2 = Wi2 + (size_t)jdu * 64;
    const float* Wa2 = Wf2 + (size_t)(2 * jdu) * 64;
    const float* Wb2 = Wf2 + (size_t)(2 * jdu + 1) * 64;
    float b[24];
#pragma unroll
    for (int i = 0; i < 8; ++i) {
        b[i]      = bi2[jdu * 8 + i];
        b[8 + i]  = bf2[(2 * jdu) * 8 + i];
        b[16 + i] = bf2[(2 * jdu + 1) * 8 + i];
    }
#pragma unroll
    for (int k = 0; k < 8; ++k) {
#pragma unroll
        for (int i = 0; i < 8; ++i) {
            b[i]      = fmaf(Wg2[i * 8 + k], h[k],      b[i]);
            b[8 + i]  = fmaf(Wa2[i * 8 + k], h[8 + k],  b[8 + i]);
            b[16 + i] = fmaf(Wb2[i * 8 + k], h[16 + k], b[16 + i]);
        }
    }
#pragma unroll
    for (int i = 0; i < 24; ++i) h[i] = tanh_(b[i]);

    // ---------------- Phase 3: L3 of all three nets ----------------
    float g0 = bi3[jdu * 2 + 0], g1 = bi3[jdu * 2 + 1];
    {
        const float* Wg3 = Wi3 + (size_t)jdu * 16;
#pragma unroll
        for (int k = 0; k < 8; ++k) {
            g0 = fmaf(Wg3[k],     h[k], g0);
            g1 = fmaf(Wg3[8 + k], h[k], g1);
        }
    }
    float o0[14], o1[14];
    {
        const float* Wa3 = Wf3 + (size_t)(2 * jdu) * 112;
        const float* ba3 = bf3 + (2 * jdu) * 14;
        const float* Wb3 = Wf3 + (size_t)(2 * jdu + 1) * 112;
        const float* bb3 = bf3 + (2 * jdu + 1) * 14;
#pragma unroll
        for (int i = 0; i < 14; ++i) {
            float acc = ba3[i];
#pragma unroll
            for (int k = 0; k < 8; ++k) acc = fmaf(Wa3[i * 8 + k], h[8 + k], acc);
            o0[i] = acc;
        }
#pragma unroll
        for (int i = 0; i < 14; ++i) {
            float acc = bb3[i];
#pragma unroll
            for (int k = 0; k < 8; ++k) acc = fmaf(Wb3[i * 8 + k], h[16 + k], acc);
            o1[i] = acc;
        }
    }

    // ---------------- splines (sequential in x) ----------------
    float ldsum = 0.0f;
    auto spline = [&](const float* __restrict__ o) {
        float wv[5], hv[5];
        dsm5_(o[0], o[1], o[2], o[3], o[4], wv);
        dsm5_(o[5], o[6], o[7], o[8], o[9], hv);
        float di1 = sp2_(o[10]) + 0.001f;
        float di2 = sp2_(o[11]) + 0.001f;
        float di3 = sp2_(o[12]) + 0.001f;
        float di4 = sp2_(o[13]) + 0.001f;

        float xc = fminf(fmaxf(xcur, -3.0f), 3.0f);

        float runw = wv[0], runh = hv[0];
        float cwL = -3.0f, chL = -3.0f;
        float cwR = fmaf(6.0f, runw, -3.0f);
        float chR = fmaf(6.0f, runh, -3.0f);
        float icw = cwL, ibw = cwR - cwL, ich = chL, ihh = chR - chL;
        float d0 = 1.0f, d1 = di1;
#pragma unroll
        for (int k = 1; k < 5; ++k) {
            cwL = cwR; chL = chR;
            runw += wv[k]; runh += hv[k];
            cwR = (k == 4) ? 3.0f : fmaf(6.0f, runw, -3.0f);
            chR = (k == 4) ? 3.0f : fmaf(6.0f, runh, -3.0f);
            float dk0 = (k == 1) ? di1 : (k == 2) ? di2 : (k == 3) ? di3 : di4;
            float dk1 = (k == 1) ? di2 : (k == 2) ? di3 : (k == 3) ? di4 : 1.0f;
            bool sel = (xc >= cwL);
            icw = sel ? cwL : icw;
            ibw = sel ? (cwR - cwL) : ibw;
            ich = sel ? chL : ich;
            ihh = sel ? (chR - chL) : ihh;
            d0  = sel ? dk0 : d0;
            d1  = sel ? dk1 : d1;
        }

        float rb     = rcp_(ibw);
        float idelta = ihh * rb;
        float th     = (xc - icw) * rb;
        float t2     = th * th;
        float omt    = 1.0f - th;
        float tomt   = th * omt;
        float den    = fmaf(fmaf(-2.0f, idelta, d0 + d1), tomt, idelta);
        float rden   = rcp_(den);
        float xn     = fmaf(ihh * fmaf(idelta, t2, d0 * tomt), rden, ich);
        float num    = (idelta * idelta) *
                       fmaf(d1, t2, fmaf(idelta + idelta, tomt, d0 * (omt * omt)));
        float ldi    = __logf((num * rden) * rden);

        bool inside = (xcur >= -3.0f) && (xcur <= 3.0f);
        xcur  = inside ? xn : xcur;
        ldsum = inside ? (ldsum + ldi) : ldsum;
    };
    spline(o0);
    spline(o1);

    // ---------------- gaussian base log-prob ----------------
    float z  = (xcur - g0) * __expf(-g1);
    float ez = __expf(-z);
    float lp = -(z + ez) - g1;
    if (isnan(lp) || isinf(lp)) lp = -100.0f;
    float col = ldsum + lp;

    // ---------------- cross-dim reduction ----------------
    __shared__ float red[8][64];
    red[jd][lane] = col;
    __syncthreads();
    if (jd == 0 && s < N) {
        float acc = red[0][lane];
#pragma unroll
        for (int j = 1; j < 8; ++j) acc += red[j][lane];
        out[s] = acc;
    }
}

extern "C" void kernel_launch(void* const* d_in, const int* in_sizes, int n_in,
                              void* d_out, int out_size, void* d_ws, size_t ws_size,
                              hipStream_t stream) {
    const float* x_inp    = (const float*)d_in[0];
    const float* cond_inp = (const float*)d_in[1];
    const float* Wi1 = (const float*)d_in[2];
    const float* bi1 = (const float*)d_in[3];
    const float* Wi2 = (const float*)d_in[4];
    const float* bi2 = (const float*)d_in[5];
    const float* Wi3 = (const float*)d_in[6];
    const float* bi3 = (const float*)d_in[7];
    const float* Wf1 = (const float*)d_in[8];
    const float* bf1 = (const float*)d_in[9];
    const float* Wf2 = (const float*)d_in[10];
    const float* bf2 = (const float*)d_in[11];
    const float* Wf3 = (const float*)d_in[12];
    const float* bf3 = (const float*)d_in[13];
    float* out = (float*)d_out;

    int N = out_size;
    int grid = (N + 63) / 64;
    dim3 block(64, 8, 1);
    hipLaunchKernelGGL(nsf_kernel, dim3(grid), block, 0, stream,
                       x_inp, cond_inp, Wi1, bi1, Wi2, bi2, Wi3, bi3,
                       Wf1, bf1, Wf2, bf2, Wf3, bf3, out, N);
}

// Round 10
// 268.208 us; speedup vs baseline: 1.2155x; 1.2155x over previous
//
#include <hip/hip_runtime.h>
#include <math.h>

__device__ __forceinline__ float rcp_(float x) { return __fdividef(1.0f, x); }

// tanh via [9/8] continued-fraction Pade, t = x^2; 1 rcp, no exp.
__device__ __forceinline__ float tanh_(float x) {
    float t = x * x;
    float p = t + 378.0f;
    p = fmaf(p, t, 17325.0f);
    p = fmaf(p, t, 135135.0f);
    float q = fmaf(28.0f, t, 3150.0f);
    q = fmaf(q, t, 62370.0f);
    q = fmaf(q, t, 135135.0f);
    float r = (x * p) * rcp_(q);
    return fminf(fmaxf(r, -1.0f), 1.0f);
}

// EXACT: softplus(softplus(x)) = log(2 + e^x)
__device__ __forceinline__ float sp2_(float x) {
    return __logf(2.0f + __expf(x));
}

// w[k] = 0.001 + 0.995 * softmax(6*softmax(o))[k]; shift-invariance -> no max needed
__device__ __forceinline__ void dsm5_(float o0, float o1, float o2, float o3, float o4,
                                      float* __restrict__ w) {
    float e0 = __expf(o0), e1 = __expf(o1), e2 = __expf(o2),
          e3 = __expf(o3), e4 = __expf(o4);
    float inv = 6.0f * rcp_(((e0 + e1) + (e2 + e3)) + e4);
    float f0 = __expf(e0 * inv);
    float f1 = __expf(e1 * inv);
    float f2 = __expf(e2 * inv);
    float f3 = __expf(e3 * inv);
    float f4 = __expf(e4 * inv);
    float t = 0.995f * rcp_(((f0 + f1) + (f2 + f3)) + f4);
    w[0] = fmaf(f0, t, 0.001f);
    w[1] = fmaf(f1, t, 0.001f);
    w[2] = fmaf(f2, t, 0.001f);
    w[3] = fmaf(f3, t, 0.001f);
    w[4] = fmaf(f4, t, 0.001f);
}

__global__ __launch_bounds__(512)
void zero_out(float* __restrict__ out, int n4) {
    int i = blockIdx.x * blockDim.x + threadIdx.x;
    if (i < n4) ((float4*)out)[i] = (float4){0.0f, 0.0f, 0.0f, 0.0f};
}

__global__ __launch_bounds__(512)
void nsf_kernel(const float* __restrict__ x_inp, const float* __restrict__ cond_inp,
                const float* __restrict__ Wi1, const float* __restrict__ bi1,
                const float* __restrict__ Wi2, const float* __restrict__ bi2,
                const float* __restrict__ Wi3, const float* __restrict__ bi3,
                const float* __restrict__ Wf1, const float* __restrict__ bf1,
                const float* __restrict__ Wf2, const float* __restrict__ bf2,
                const float* __restrict__ Wf3, const float* __restrict__ bf3,
                float* __restrict__ out, int N)
{
    const int jd = blockIdx.y;            // one dim per block: ALL 8 waves share one
                                          // ~4.3KB weight stream -> scalar-K$ resident
    int s = blockIdx.x * 512 + threadIdx.x;
    int sl = (s < N) ? s : (N - 1);

    // ---- per-sample inputs ----
    float cond[23];
    float xcur;
    {
        const float4* cp = (const float4*)(cond_inp + (size_t)sl * 16);
        float4 c0 = cp[0], c1 = cp[1], c2 = cp[2], c3 = cp[3];
        cond[0]=c0.x;  cond[1]=c0.y;  cond[2]=c0.z;  cond[3]=c0.w;
        cond[4]=c1.x;  cond[5]=c1.y;  cond[6]=c1.z;  cond[7]=c1.w;
        cond[8]=c2.x;  cond[9]=c2.y;  cond[10]=c2.z; cond[11]=c2.w;
        cond[12]=c3.x; cond[13]=c3.y; cond[14]=c3.z; cond[15]=c3.w;

        const float4* xp = (const float4*)(x_inp + (size_t)sl * 8);
        float4 a = xp[0], b = xp[1];
        float xv[8] = {a.x, a.y, a.z, a.w, b.x, b.y, b.z, b.w};
#pragma unroll
        for (int t = 0; t < 7; ++t)
            cond[16 + t] = (t < jd) ? xv[t] : 0.0f;
        xcur = xv[0];
#pragma unroll
        for (int t = 1; t < 8; ++t) xcur = (jd == t) ? xv[t] : xcur;
    }

    // ---------- gaussian-base network ----------
    float g0, g1;
    {
        const float* W1 = Wi1 + (size_t)jd * 184;
        const float* b1 = bi1 + jd * 8;
        const float* W2 = Wi2 + (size_t)jd * 64;
        const float* b2 = bi2 + jd * 8;
        const float* W3 = Wi3 + (size_t)jd * 16;
        const float* b3 = bi3 + jd * 2;
        float h1[8], h2[8];
#pragma unroll
        for (int i = 0; i < 8; ++i) {
            float a = b1[i];
#pragma unroll
            for (int c = 0; c < 23; ++c) a = fmaf(W1[i * 23 + c], cond[c], a);
            h1[i] = tanh_(a);
        }
#pragma unroll
        for (int i = 0; i < 8; ++i) {
            float a = b2[i];
#pragma unroll
            for (int c = 0; c < 8; ++c) a = fmaf(W2[i * 8 + c], h1[c], a);
            h2[i] = tanh_(a);
        }
        g0 = b3[0]; g1 = b3[1];
#pragma unroll
        for (int c = 0; c < 8; ++c) {
            g0 = fmaf(W3[c], h2[c], g0);
            g1 = fmaf(W3[8 + c], h2[c], g1);
        }
    }

    // ---------- flows ----------
    float ldsum = 0.0f;
#pragma unroll
    for (int jf = 0; jf < 2; ++jf) {
        const int nf = jd * 2 + jf;
        const float* F1  = Wf1 + (size_t)nf * 184;
        const float* fb1 = bf1 + nf * 8;
        const float* F2  = Wf2 + (size_t)nf * 64;
        const float* fb2 = bf2 + nf * 8;
        const float* F3  = Wf3 + (size_t)nf * 112;
        const float* fb3 = bf3 + nf * 14;

        float h1[8], h2[8];
#pragma unroll
        for (int i = 0; i < 8; ++i) {
            float a = fb1[i];
#pragma unroll
            for (int c = 0; c < 23; ++c) a = fmaf(F1[i * 23 + c], cond[c], a);
            h1[i] = tanh_(a);
        }
#pragma unroll
        for (int i = 0; i < 8; ++i) {
            float a = fb2[i];
#pragma unroll
            for (int c = 0; c < 8; ++c) a = fmaf(F2[i * 8 + c], h1[c], a);
            h2[i] = tanh_(a);
        }
        float o[14];
#pragma unroll
        for (int i = 0; i < 14; ++i) {
            float a = fb3[i];
#pragma unroll
            for (int c = 0; c < 8; ++c) a = fmaf(F3[i * 8 + c], h2[c], a);
            o[i] = a;
        }

        // ---------- RQS spline ----------
        float wv[5], hv[5];
        dsm5_(o[0], o[1], o[2], o[3], o[4], wv);
        dsm5_(o[5], o[6], o[7], o[8], o[9], hv);
        float di1 = sp2_(o[10]) + 0.001f;
        float di2 = sp2_(o[11]) + 0.001f;
        float di3 = sp2_(o[12]) + 0.001f;
        float di4 = sp2_(o[13]) + 0.001f;

        float xc = fminf(fmaxf(xcur, -3.0f), 3.0f);

        float runw = wv[0], runh = hv[0];
        float cwL = -3.0f, chL = -3.0f;
        float cwR = fmaf(6.0f, runw, -3.0f);
        float chR = fmaf(6.0f, runh, -3.0f);
        float icw = cwL, ibw = cwR - cwL, ich = chL, ihh = chR - chL;
        float d0 = 1.0f, d1 = di1;
#pragma unroll
        for (int k = 1; k < 5; ++k) {
            cwL = cwR; chL = chR;
            runw += wv[k]; runh += hv[k];
            cwR = (k == 4) ? 3.0f : fmaf(6.0f, runw, -3.0f);
            chR = (k == 4) ? 3.0f : fmaf(6.0f, runh, -3.0f);
            float dk0 = (k == 1) ? di1 : (k == 2) ? di2 : (k == 3) ? di3 : di4;
            float dk1 = (k == 1) ? di2 : (k == 2) ? di3 : (k == 3) ? di4 : 1.0f;
            bool sel = (xc >= cwL);
            icw = sel ? cwL : icw;
            ibw = sel ? (cwR - cwL) : ibw;
            ich = sel ? chL : ich;
            ihh = sel ? (chR - chL) : ihh;
            d0  = sel ? dk0 : d0;
            d1  = sel ? dk1 : d1;
        }

        float rb     = rcp_(ibw);
        float idelta = ihh * rb;
        float th     = (xc - icw) * rb;
        float t2     = th * th;
        float omt    = 1.0f - th;
        float tomt   = th * omt;
        float den    = fmaf(fmaf(-2.0f, idelta, d0 + d1), tomt, idelta);
        float rden   = rcp_(den);
        float xn     = fmaf(ihh * fmaf(idelta, t2, d0 * tomt), rden, ich);
        float num    = (idelta * idelta) *
                       fmaf(d1, t2, fmaf(idelta + idelta, tomt, d0 * (omt * omt)));
        float ldi    = __logf((num * rden) * rden);

        bool inside = (xcur >= -3.0f) && (xcur <= 3.0f);
        xcur  = inside ? xn : xcur;
        ldsum = inside ? (ldsum + ldi) : ldsum;
    }

    // ---------- gaussian base log-prob ----------
    float z  = (xcur - g0) * __expf(-g1);
    float ez = __expf(-z);
    float lp = -(z + ez) - g1;
    if (isnan(lp) || isinf(lp)) lp = -100.0f;

    if (s < N) atomicAdd(&out[s], ldsum + lp);   // device-scope, 8 adds/output
}

extern "C" void kernel_launch(void* const* d_in, const int* in_sizes, int n_in,
                              void* d_out, int out_size, void* d_ws, size_t ws_size,
                              hipStream_t stream) {
    const float* x_inp    = (const float*)d_in[0];
    const float* cond_inp = (const float*)d_in[1];
    const float* Wi1 = (const float*)d_in[2];
    const float* bi1 = (const float*)d_in[3];
    const float* Wi2 = (const float*)d_in[4];
    const float* bi2 = (const float*)d_in[5];
    const float* Wi3 = (const float*)d_in[6];
    const float* bi3 = (const float*)d_in[7];
    const float* Wf1 = (const float*)d_in[8];
    const float* bf1 = (const float*)d_in[9];
    const float* Wf2 = (const float*)d_in[10];
    const float* bf2 = (const float*)d_in[11];
    const float* Wf3 = (const float*)d_in[12];
    const float* bf3 = (const float*)d_in[13];
    float* out = (float*)d_out;

    int N = out_size;
    int n4 = N / 4;
    hipLaunchKernelGGL(zero_out, dim3((n4 + 511) / 512), dim3(512), 0, stream, out, n4);

    dim3 grid((N + 511) / 512, 8, 1);
    hipLaunchKernelGGL(nsf_kernel, grid, dim3(512), 0, stream,
                       x_inp, cond_inp, Wi1, bi1, Wi2, bi2, Wi3, bi3,
                       Wf1, bf1, Wf2, bf2, Wf3, bf3, out, N);
}

// Round 11
// 248.565 us; speedup vs baseline: 1.3115x; 1.0790x over previous
//
#include <hip/hip_runtime.h>
#include <math.h>

__device__ __forceinline__ float rcp_(float x) { return __fdividef(1.0f, x); }

// tanh via [9/8] continued-fraction Pade, t = x^2; 1 rcp, no exp.
__device__ __forceinline__ float tanh_(float x) {
    float t = x * x;
    float p = t + 378.0f;
    p = fmaf(p, t, 17325.0f);
    p = fmaf(p, t, 135135.0f);
    float q = fmaf(28.0f, t, 3150.0f);
    q = fmaf(q, t, 62370.0f);
    q = fmaf(q, t, 135135.0f);
    float r = (x * p) * rcp_(q);
    return fminf(fmaxf(r, -1.0f), 1.0f);
}

// EXACT: softplus(softplus(x)) = log(2 + e^x)
__device__ __forceinline__ float sp2_(float x) {
    return __logf(2.0f + __expf(x));
}

// w[k] = 0.001 + 0.995 * softmax(6*softmax(o))[k]; shift-invariance -> no max needed
__device__ __forceinline__ void dsm5_(float o0, float o1, float o2, float o3, float o4,
                                      float* __restrict__ w) {
    float e0 = __expf(o0), e1 = __expf(o1), e2 = __expf(o2),
          e3 = __expf(o3), e4 = __expf(o4);
    float inv = 6.0f * rcp_(((e0 + e1) + (e2 + e3)) + e4);
    float f0 = __expf(e0 * inv);
    float f1 = __expf(e1 * inv);
    float f2 = __expf(e2 * inv);
    float f3 = __expf(e3 * inv);
    float f4 = __expf(e4 * inv);
    float t = 0.995f * rcp_(((f0 + f1) + (f2 + f3)) + f4);
    w[0] = fmaf(f0, t, 0.001f);
    w[1] = fmaf(f1, t, 0.001f);
    w[2] = fmaf(f2, t, 0.001f);
    w[3] = fmaf(f3, t, 0.001f);
    w[4] = fmaf(f4, t, 0.001f);
}

__global__ __launch_bounds__(1024)
void nsf_kernel(const float* __restrict__ x_inp, const float* __restrict__ cond_inp,
                const float* __restrict__ Wi1, const float* __restrict__ bi1,
                const float* __restrict__ Wi2, const float* __restrict__ bi2,
                const float* __restrict__ Wi3, const float* __restrict__ bi3,
                const float* __restrict__ Wf1, const float* __restrict__ bf1,
                const float* __restrict__ Wf2, const float* __restrict__ bf2,
                const float* __restrict__ Wf3, const float* __restrict__ bf3,
                float* __restrict__ out, int N)
{
    const int lane = threadIdx.x;                 // 0..63 sample-in-block
    const int jd   = threadIdx.y;                 // 0..7 dim
    const int nz   = threadIdx.z;                 // 0: flow0+gauss, 1: flow1+splines
    const int jdu  = __builtin_amdgcn_readfirstlane(jd);
    const int nzu  = __builtin_amdgcn_readfirstlane(nz);
    int s = blockIdx.x * 64 + lane;
    int sl = (s < N) ? s : (N - 1);

    __shared__ float o0s[8][64][14];   // flow0 MLP outputs, z0 -> z1
    __shared__ float gs[8][64][2];     // gaussian g0,g1,  z0 -> z1
    __shared__ float red[8][64];       // cross-dim reduction

    // ---- per-sample inputs ----
    float cond[23];
    float xcur;
    {
        const float4* cp = (const float4*)(cond_inp + (size_t)sl * 16);
        float4 c0 = cp[0], c1 = cp[1], c2 = cp[2], c3 = cp[3];
        cond[0]=c0.x;  cond[1]=c0.y;  cond[2]=c0.z;  cond[3]=c0.w;
        cond[4]=c1.x;  cond[5]=c1.y;  cond[6]=c1.z;  cond[7]=c1.w;
        cond[8]=c2.x;  cond[9]=c2.y;  cond[10]=c2.z; cond[11]=c2.w;
        cond[12]=c3.x; cond[13]=c3.y; cond[14]=c3.z; cond[15]=c3.w;

        const float4* xp = (const float4*)(x_inp + (size_t)sl * 8);
        float4 a = xp[0], b = xp[1];
        float xv[8] = {a.x, a.y, a.z, a.w, b.x, b.y, b.z, b.w};
#pragma unroll
        for (int t = 0; t < 7; ++t)
            cond[16 + t] = (t < jd) ? xv[t] : 0.0f;
        xcur = xv[0];
#pragma unroll
        for (int t = 1; t < 8; ++t) xcur = (jd == t) ? xv[t] : xcur;
    }

    // ---------- phase 1: one flow-MLP per z (z0 -> flow0, z1 -> flow1) ----------
    float o[14];
    {
        const int nf = 2 * jdu + nzu;
        const float* F1  = Wf1 + (size_t)nf * 184;
        const float* fb1 = bf1 + nf * 8;
        const float* F2  = Wf2 + (size_t)nf * 64;
        const float* fb2 = bf2 + nf * 8;
        const float* F3  = Wf3 + (size_t)nf * 112;
        const float* fb3 = bf3 + nf * 14;

        float h1[8], h2[8];
#pragma unroll
        for (int i = 0; i < 8; ++i) {
            float a = fb1[i];
#pragma unroll
            for (int c = 0; c < 23; ++c) a = fmaf(F1[i * 23 + c], cond[c], a);
            h1[i] = tanh_(a);
        }
#pragma unroll
        for (int i = 0; i < 8; ++i) {
            float a = fb2[i];
#pragma unroll
            for (int c = 0; c < 8; ++c) a = fmaf(F2[i * 8 + c], h1[c], a);
            h2[i] = tanh_(a);
        }
#pragma unroll
        for (int i = 0; i < 14; ++i) {
            float a = fb3[i];
#pragma unroll
            for (int c = 0; c < 8; ++c) a = fmaf(F3[i * 8 + c], h2[c], a);
            o[i] = a;
        }
    }
    if (nz == 0) {
#pragma unroll
        for (int i = 0; i < 14; ++i) o0s[jd][lane][i] = o[i];
    }
    __syncthreads();

    float col = 0.0f;
    if (nz == 0) {
        // ---------- phase 2a (z0): gaussian-base net ----------
        const float* W1 = Wi1 + (size_t)jdu * 184;
        const float* b1 = bi1 + jdu * 8;
        const float* W2 = Wi2 + (size_t)jdu * 64;
        const float* b2 = bi2 + jdu * 8;
        const float* W3 = Wi3 + (size_t)jdu * 16;
        const float* b3 = bi3 + jdu * 2;
        float h1[8], h2[8];
#pragma unroll
        for (int i = 0; i < 8; ++i) {
            float a = b1[i];
#pragma unroll
            for (int c = 0; c < 23; ++c) a = fmaf(W1[i * 23 + c], cond[c], a);
            h1[i] = tanh_(a);
        }
#pragma unroll
        for (int i = 0; i < 8; ++i) {
            float a = b2[i];
#pragma unroll
            for (int c = 0; c < 8; ++c) a = fmaf(W2[i * 8 + c], h1[c], a);
            h2[i] = tanh_(a);
        }
        float g0 = b3[0], g1 = b3[1];
#pragma unroll
        for (int c = 0; c < 8; ++c) {
            g0 = fmaf(W3[c], h2[c], g0);
            g1 = fmaf(W3[8 + c], h2[c], g1);
        }
        gs[jd][lane][0] = g0;
        gs[jd][lane][1] = g1;
    } else {
        // ---------- phase 2b (z1): both splines ----------
        float ldsum = 0.0f;
        auto spline = [&](const float* __restrict__ oo) {
            float wv[5], hv[5];
            dsm5_(oo[0], oo[1], oo[2], oo[3], oo[4], wv);
            dsm5_(oo[5], oo[6], oo[7], oo[8], oo[9], hv);
            float di1 = sp2_(oo[10]) + 0.001f;
            float di2 = sp2_(oo[11]) + 0.001f;
            float di3 = sp2_(oo[12]) + 0.001f;
            float di4 = sp2_(oo[13]) + 0.001f;

            float xc = fminf(fmaxf(xcur, -3.0f), 3.0f);

            float runw = wv[0], runh = hv[0];
            float cwL = -3.0f, chL = -3.0f;
            float cwR = fmaf(6.0f, runw, -3.0f);
            float chR = fmaf(6.0f, runh, -3.0f);
            float icw = cwL, ibw = cwR - cwL, ich = chL, ihh = chR - chL;
            float d0 = 1.0f, d1 = di1;
#pragma unroll
            for (int k = 1; k < 5; ++k) {
                cwL = cwR; chL = chR;
                runw += wv[k]; runh += hv[k];
                cwR = (k == 4) ? 3.0f : fmaf(6.0f, runw, -3.0f);
                chR = (k == 4) ? 3.0f : fmaf(6.0f, runh, -3.0f);
                float dk0 = (k == 1) ? di1 : (k == 2) ? di2 : (k == 3) ? di3 : di4;
                float dk1 = (k == 1) ? di2 : (k == 2) ? di3 : (k == 3) ? di4 : 1.0f;
                bool sel = (xc >= cwL);
                icw = sel ? cwL : icw;
                ibw = sel ? (cwR - cwL) : ibw;
                ich = sel ? chL : ich;
                ihh = sel ? (chR - chL) : ihh;
                d0  = sel ? dk0 : d0;
                d1  = sel ? dk1 : d1;
            }

            float rb     = rcp_(ibw);
            float idelta = ihh * rb;
            float th     = (xc - icw) * rb;
            float t2     = th * th;
            float omt    = 1.0f - th;
            float tomt   = th * omt;
            float den    = fmaf(fmaf(-2.0f, idelta, d0 + d1), tomt, idelta);
            float rden   = rcp_(den);
            float xn     = fmaf(ihh * fmaf(idelta, t2, d0 * tomt), rden, ich);
            float num    = (idelta * idelta) *
                           fmaf(d1, t2, fmaf(idelta + idelta, tomt, d0 * (omt * omt)));
            float ldi    = __logf((num * rden) * rden);

            bool inside = (xcur >= -3.0f) && (xcur <= 3.0f);
            xcur  = inside ? xn : xcur;
            ldsum = inside ? (ldsum + ldi) : ldsum;
        };
        float oo[14];
#pragma unroll
        for (int i = 0; i < 14; ++i) oo[i] = o0s[jd][lane][i];
        spline(oo);   // flow0 (from z0 via LDS)
        spline(o);    // flow1 (own registers)
        col = ldsum;  // base logp added after the g barrier
    }
    __syncthreads();

    if (nz == 1) {
        float g0 = gs[jd][lane][0];
        float g1 = gs[jd][lane][1];
        float z  = (xcur - g0) * __expf(-g1);
        float ez = __expf(-z);
        float lp = -(z + ez) - g1;
        if (isnan(lp) || isinf(lp)) lp = -100.0f;
        red[jd][lane] = col + lp;
    }
    __syncthreads();

    if (nz == 1 && jd == 0 && s < N) {
        float acc = red[0][lane];
#pragma unroll
        for (int j = 1; j < 8; ++j) acc += red[j][lane];
        out[s] = acc;
    }
}

extern "C" void kernel_launch(void* const* d_in, const int* in_sizes, int n_in,
                              void* d_out, int out_size, void* d_ws, size_t ws_size,
                              hipStream_t stream) {
    const float* x_inp    = (const float*)d_in[0];
    const float* cond_inp = (const float*)d_in[1];
    const float* Wi1 = (const float*)d_in[2];
    const float* bi1 = (const float*)d_in[3];
    const float* Wi2 = (const float*)d_in[4];
    const float* bi2 = (const float*)d_in[5];
    const float* Wi3 = (const float*)d_in[6];
    const float* bi3 = (const float*)d_in[7];
    const float* Wf1 = (const float*)d_in[8];
    const float* bf1 = (const float*)d_in[9];
    const float* Wf2 = (const float*)d_in[10];
    const float* bf2 = (const float*)d_in[11];
    const float* Wf3 = (const float*)d_in[12];
    const float* bf3 = (const float*)d_in[13];
    float* out = (float*)d_out;

    int N = out_size;
    int grid = (N + 63) / 64;
    dim3 block(64, 8, 2);
    hipLaunchKernelGGL(nsf_kernel, dim3(grid), block, 0, stream,
                       x_inp, cond_inp, Wi1, bi1, Wi2, bi2, Wi3, bi3,
                       Wf1, bf1, Wf2, bf2, Wf3, bf3, out, N);
}

// Round 12
// 234.394 us; speedup vs baseline: 1.3908x; 1.0605x over previous
//
#include <hip/hip_runtime.h>
#include <math.h>

typedef float v2 __attribute__((ext_vector_type(2)));

__device__ __forceinline__ float rcp1_(float x) { return __fdividef(1.0f, x); }
__device__ __forceinline__ v2 v2s(float s) { return (v2){s, s}; }
__device__ __forceinline__ v2 expv(v2 x) { return (v2){__expf(x.x), __expf(x.y)}; }
__device__ __forceinline__ v2 logv(v2 x) { return (v2){__logf(x.x), __logf(x.y)}; }
__device__ __forceinline__ v2 rcpv(v2 x) { return (v2){rcp1_(x.x), rcp1_(x.y)}; }
__device__ __forceinline__ v2 maxv(v2 a, v2 b) { return __builtin_elementwise_max(a, b); }
__device__ __forceinline__ v2 minv(v2 a, v2 b) { return __builtin_elementwise_min(a, b); }

// componentwise select: (x >= e) ? a : b
__device__ __forceinline__ v2 selge(v2 x, v2 e, v2 a, v2 b) {
    v2 r;
    r.x = (x.x >= e.x) ? a.x : b.x;
    r.y = (x.y >= e.y) ? a.y : b.y;
    return r;
}

// tanh via [9/8] continued-fraction Pade, t = x^2; 1 rcp, no exp.
__device__ __forceinline__ v2 tanhv(v2 x) {
    v2 t = x * x;
    v2 p = t + v2s(378.0f);
    p = p * t + v2s(17325.0f);
    p = p * t + v2s(135135.0f);
    v2 q = v2s(28.0f) * t + v2s(3150.0f);
    q = q * t + v2s(62370.0f);
    q = q * t + v2s(135135.0f);
    v2 r = (x * p) * rcpv(q);
    return minv(maxv(r, v2s(-1.0f)), v2s(1.0f));
}

// EXACT: softplus(softplus(x)) = log(2 + e^x)
__device__ __forceinline__ v2 sp2v(v2 x) {
    return logv(v2s(2.0f) + expv(x));
}

// w[k] = 0.001 + 0.995*softmax(6*softmax(o))[k]; shift-invariance -> no max anywhere
__device__ __forceinline__ void dsm5v(v2 o0, v2 o1, v2 o2, v2 o3, v2 o4, v2* __restrict__ w) {
    v2 e0 = expv(o0), e1 = expv(o1), e2 = expv(o2), e3 = expv(o3), e4 = expv(o4);
    v2 inv = v2s(6.0f) * rcpv(((e0 + e1) + (e2 + e3)) + e4);
    v2 f0 = expv(e0 * inv);
    v2 f1 = expv(e1 * inv);
    v2 f2 = expv(e2 * inv);
    v2 f3 = expv(e3 * inv);
    v2 f4 = expv(e4 * inv);
    v2 t = v2s(0.995f) * rcpv(((f0 + f1) + (f2 + f3)) + f4);
    w[0] = f0 * t + v2s(0.001f);
    w[1] = f1 * t + v2s(0.001f);
    w[2] = f2 * t + v2s(0.001f);
    w[3] = f3 * t + v2s(0.001f);
    w[4] = f4 * t + v2s(0.001f);
}

__global__ __launch_bounds__(512)
void nsf_kernel(const float* __restrict__ x_inp, const float* __restrict__ cond_inp,
                const float* __restrict__ Wi1, const float* __restrict__ bi1,
                const float* __restrict__ Wi2, const float* __restrict__ bi2,
                const float* __restrict__ Wi3, const float* __restrict__ bi3,
                const float* __restrict__ Wf1, const float* __restrict__ bf1,
                const float* __restrict__ Wf2, const float* __restrict__ bf2,
                const float* __restrict__ Wf3, const float* __restrict__ bf3,
                float* __restrict__ out, int N)
{
    const int lane = threadIdx.x;                 // 0..63 pair-in-block
    const int jd   = threadIdx.y;                 // 0..7 dim (one wave per dim)
    const int jdu  = __builtin_amdgcn_readfirstlane(jd);
    int p = blockIdx.x * 64 + lane;               // pair index
    int s0 = 2 * p;
    int sa = (s0 < N) ? s0 : (N - 2);             // N even; guard store below
    int sb = sa + 1;

    // ---- per-sample inputs, packed 2-wide ----
    v2 cond[23];
    v2 xcur;
    {
        const float4* ca = (const float4*)(cond_inp + (size_t)sa * 16);
        const float4* cb = (const float4*)(cond_inp + (size_t)sb * 16);
#pragma unroll
        for (int q = 0; q < 4; ++q) {
            float4 u = ca[q], v = cb[q];
            cond[4 * q + 0] = (v2){u.x, v.x};
            cond[4 * q + 1] = (v2){u.y, v.y};
            cond[4 * q + 2] = (v2){u.z, v.z};
            cond[4 * q + 3] = (v2){u.w, v.w};
        }
        const float4* xa = (const float4*)(x_inp + (size_t)sa * 8);
        const float4* xb = (const float4*)(x_inp + (size_t)sb * 8);
        float4 a0 = xa[0], a1 = xa[1], b0 = xb[0], b1 = xb[1];
        v2 xv[8];
        xv[0] = (v2){a0.x, b0.x}; xv[1] = (v2){a0.y, b0.y};
        xv[2] = (v2){a0.z, b0.z}; xv[3] = (v2){a0.w, b0.w};
        xv[4] = (v2){a1.x, b1.x}; xv[5] = (v2){a1.y, b1.y};
        xv[6] = (v2){a1.z, b1.z}; xv[7] = (v2){a1.w, b1.w};
#pragma unroll
        for (int t = 0; t < 7; ++t)
            cond[16 + t] = (t < jd) ? xv[t] : v2s(0.0f);
        xcur = xv[0];
#pragma unroll
        for (int t = 1; t < 8; ++t) xcur = (jd == t) ? xv[t] : xcur;
    }

    // ---------- gaussian-base network ----------
    v2 g0, g1;
    {
        const float* W1 = Wi1 + (size_t)jdu * 184;
        const float* b1 = bi1 + jdu * 8;
        const float* W2 = Wi2 + (size_t)jdu * 64;
        const float* b2 = bi2 + jdu * 8;
        const float* W3 = Wi3 + (size_t)jdu * 16;
        const float* b3 = bi3 + jdu * 2;
        v2 h1[8], h2[8];
#pragma unroll
        for (int i = 0; i < 8; ++i) {
            v2 a = v2s(b1[i]);
#pragma unroll
            for (int c = 0; c < 23; ++c) a = v2s(W1[i * 23 + c]) * cond[c] + a;
            h1[i] = tanhv(a);
        }
#pragma unroll
        for (int i = 0; i < 8; ++i) {
            v2 a = v2s(b2[i]);
#pragma unroll
            for (int c = 0; c < 8; ++c) a = v2s(W2[i * 8 + c]) * h1[c] + a;
            h2[i] = tanhv(a);
        }
        g0 = v2s(b3[0]); g1 = v2s(b3[1]);
#pragma unroll
        for (int c = 0; c < 8; ++c) {
            g0 = v2s(W3[c]) * h2[c] + g0;
            g1 = v2s(W3[8 + c]) * h2[c] + g1;
        }
    }

    // ---------- flows ----------
    v2 ldsum = v2s(0.0f);
#pragma unroll
    for (int jf = 0; jf < 2; ++jf) {
        const int nf = jdu * 2 + jf;
        const float* F1  = Wf1 + (size_t)nf * 184;
        const float* fb1 = bf1 + nf * 8;
        const float* F2  = Wf2 + (size_t)nf * 64;
        const float* fb2 = bf2 + nf * 8;
        const float* F3  = Wf3 + (size_t)nf * 112;
        const float* fb3 = bf3 + nf * 14;

        v2 h1[8], h2[8];
#pragma unroll
        for (int i = 0; i < 8; ++i) {
            v2 a = v2s(fb1[i]);
#pragma unroll
            for (int c = 0; c < 23; ++c) a = v2s(F1[i * 23 + c]) * cond[c] + a;
            h1[i] = tanhv(a);
        }
#pragma unroll
        for (int i = 0; i < 8; ++i) {
            v2 a = v2s(fb2[i]);
#pragma unroll
            for (int c = 0; c < 8; ++c) a = v2s(F2[i * 8 + c]) * h1[c] + a;
            h2[i] = tanhv(a);
        }
        v2 o[14];
#pragma unroll
        for (int i = 0; i < 14; ++i) {
            v2 a = v2s(fb3[i]);
#pragma unroll
            for (int c = 0; c < 8; ++c) a = v2s(F3[i * 8 + c]) * h2[c] + a;
            o[i] = a;
        }

        // ---------- RQS spline (packed) ----------
        v2 wv[5], hv[5];
        dsm5v(o[0], o[1], o[2], o[3], o[4], wv);
        dsm5v(o[5], o[6], o[7], o[8], o[9], hv);
        v2 di1 = sp2v(o[10]) + v2s(0.001f);
        v2 di2 = sp2v(o[11]) + v2s(0.001f);
        v2 di3 = sp2v(o[12]) + v2s(0.001f);
        v2 di4 = sp2v(o[13]) + v2s(0.001f);

        v2 xc = minv(maxv(xcur, v2s(-3.0f)), v2s(3.0f));

        v2 runw = wv[0], runh = hv[0];
        v2 cwL = v2s(-3.0f), chL = v2s(-3.0f);
        v2 cwR = v2s(6.0f) * runw + v2s(-3.0f);
        v2 chR = v2s(6.0f) * runh + v2s(-3.0f);
        v2 icw = cwL, ibw = cwR - cwL, ich = chL, ihh = chR - chL;
        v2 d0 = v2s(1.0f), d1 = di1;
#pragma unroll
        for (int k = 1; k < 5; ++k) {
            cwL = cwR; chL = chR;
            runw += wv[k]; runh += hv[k];
            cwR = (k == 4) ? v2s(3.0f) : v2s(6.0f) * runw + v2s(-3.0f);
            chR = (k == 4) ? v2s(3.0f) : v2s(6.0f) * runh + v2s(-3.0f);
            v2 dk0 = (k == 1) ? di1 : (k == 2) ? di2 : (k == 3) ? di3 : di4;
            v2 dk1 = (k == 1) ? di2 : (k == 2) ? di3 : (k == 3) ? di4 : v2s(1.0f);
            icw = selge(xc, cwL, cwL, icw);
            ibw = selge(xc, cwL, cwR - cwL, ibw);
            ich = selge(xc, cwL, chL, ich);
            ihh = selge(xc, cwL, chR - chL, ihh);
            d0  = selge(xc, cwL, dk0, d0);
            d1  = selge(xc, cwL, dk1, d1);
        }

        v2 rb     = rcpv(ibw);
        v2 idelta = ihh * rb;
        v2 th     = (xc - icw) * rb;
        v2 t2     = th * th;
        v2 omt    = v2s(1.0f) - th;
        v2 tomt   = th * omt;
        v2 den    = (d0 + d1 - v2s(2.0f) * idelta) * tomt + idelta;
        v2 rden   = rcpv(den);
        v2 xn     = ihh * (idelta * t2 + d0 * tomt) * rden + ich;
        v2 num    = (idelta * idelta) *
                    (d1 * t2 + (idelta + idelta) * tomt + d0 * (omt * omt));
        v2 ldi    = logv((num * rden) * rden);

        v2 nxt, nld;
        nxt.x = (xcur.x >= -3.0f && xcur.x <= 3.0f) ? xn.x : xcur.x;
        nxt.y = (xcur.y >= -3.0f && xcur.y <= 3.0f) ? xn.y : xcur.y;
        nld.x = (xcur.x >= -3.0f && xcur.x <= 3.0f) ? (ldsum.x + ldi.x) : ldsum.x;
        nld.y = (xcur.y >= -3.0f && xcur.y <= 3.0f) ? (ldsum.y + ldi.y) : ldsum.y;
        xcur = nxt; ldsum = nld;
    }

    // ---------- gaussian base log-prob ----------
    v2 z  = (xcur - g0) * expv(-g1);
    v2 ez = expv(-z);
    v2 lp = -(z + ez) - g1;
    lp.x = (isnan(lp.x) || isinf(lp.x)) ? -100.0f : lp.x;
    lp.y = (isnan(lp.y) || isinf(lp.y)) ? -100.0f : lp.y;
    v2 col = ldsum + lp;

    // ---------- cross-dim reduction (8 waves -> 1 v2 per pair) ----------
    __shared__ v2 red[8][64];
    red[jd][lane] = col;
    __syncthreads();
    if (jd == 0 && s0 < N) {
        v2 acc = red[0][lane];
#pragma unroll
        for (int j = 1; j < 8; ++j) acc += red[j][lane];
        float2 st; st.x = acc.x; st.y = acc.y;
        *(float2*)(out + (size_t)s0) = st;
    }
}

extern "C" void kernel_launch(void* const* d_in, const int* in_sizes, int n_in,
                              void* d_out, int out_size, void* d_ws, size_t ws_size,
                              hipStream_t stream) {
    const float* x_inp    = (const float*)d_in[0];
    const float* cond_inp = (const float*)d_in[1];
    const float* Wi1 = (const float*)d_in[2];
    const float* bi1 = (const float*)d_in[3];
    const float* Wi2 = (const float*)d_in[4];
    const float* bi2 = (const float*)d_in[5];
    const float* Wi3 = (const float*)d_in[6];
    const float* bi3 = (const float*)d_in[7];
    const float* Wf1 = (const float*)d_in[8];
    const float* bf1 = (const float*)d_in[9];
    const float* Wf2 = (const float*)d_in[10];
    const float* bf2 = (const float*)d_in[11];
    const float* Wf3 = (const float*)d_in[12];
    const float* bf3 = (const float*)d_in[13];
    float* out = (float*)d_out;

    int N = out_size;
    int npairs = (N + 1) / 2;
    int grid = (npairs + 63) / 64;
    dim3 block(64, 8, 1);
    hipLaunchKernelGGL(nsf_kernel, dim3(grid), block, 0, stream,
                       x_inp, cond_inp, Wi1, bi1, Wi2, bi2, Wi3, bi3,
                       Wf1, bf1, Wf2, bf2, Wf3, bf3, out, N);
}